// Round 1
// baseline (3170.787 us; speedup 1.0000x reference)
//
#include <hip/hip_runtime.h>
#include <hip/hip_bf16.h>

#define T_STEPS 512
#define BATCH   1024
#define HD1     80
#define HD2     100
#define NB      4       // batches per block

struct F4 { float v[4]; };

// ---------------------------------------------------------------------------
// Phase 1: LSTM layer 1 (input dim 1, hidden 80). One block per 4 batches.
// 320 threads: thread j owns gate-row j (weights in registers).
// h1 state kept transposed in LDS: hT[k].v[b] = h[b][k].
// Writes relu(h1) to workspace as bf16, layout [t][b][k].
// ---------------------------------------------------------------------------
__global__ __launch_bounds__(4 * HD1, 2)
void lstm1_kernel(const float* __restrict__ x,
                  const float* __restrict__ W_ih1,
                  const float* __restrict__ W_hh1,
                  const float* __restrict__ b_ih1,
                  const float* __restrict__ b_hh1,
                  __hip_bfloat16* __restrict__ h1relu)
{
    const int j  = threadIdx.x;        // gate row 0..319
    const int b0 = blockIdx.x * NB;    // batch base
    const int q  = j / HD1;            // 0=i 1=f 2=g(tanh) 3=o
    const int m  = j % HD1;

    float w[HD1];
#pragma unroll
    for (int k = 0; k < HD1; k++) w[k] = W_hh1[j * HD1 + k];
    const float wih  = W_ih1[j];
    const float bias = b_ih1[j] + b_hh1[j];

    __shared__ F4 hT[HD1];        // h transposed: hT[k].v[b]
    __shared__ F4 gates[4 * HD1]; // gate pre-act after nonlinearity

    if (j < HD1) { hT[j].v[0] = 0.f; hT[j].v[1] = 0.f; hT[j].v[2] = 0.f; hT[j].v[3] = 0.f; }
    float c[NB] = {0.f, 0.f, 0.f, 0.f};   // cell state (threads j<HD1 use it)
    __syncthreads();

    const float* xb = x + (size_t)b0 * T_STEPS;  // x[b][t], layout (B,T,1)

    for (int t = 0; t < T_STEPS; t++) {
        float acc[NB];
#pragma unroll
        for (int b = 0; b < NB; b++)
            acc[b] = fmaf(wih, xb[(size_t)b * T_STEPS + t], bias);

#pragma unroll
        for (int k = 0; k < HD1; k++) {
            F4 hk = hT[k];
            acc[0] = fmaf(w[k], hk.v[0], acc[0]);
            acc[1] = fmaf(w[k], hk.v[1], acc[1]);
            acc[2] = fmaf(w[k], hk.v[2], acc[2]);
            acc[3] = fmaf(w[k], hk.v[3], acc[3]);
        }

        // uniform activation: tanh(x) = 2*sigmoid(2x)-1  (no wave divergence)
        F4 gv;
#pragma unroll
        for (int b = 0; b < NB; b++) {
            float z  = acc[b];
            float zz = (q == 2) ? 2.f * z : z;
            float s  = 1.f / (1.f + __expf(-zz));
            gv.v[b]  = (q == 2) ? (2.f * s - 1.f) : s;
        }
        gates[j] = gv;
        __syncthreads();

        if (j < HD1) {
            F4 gi = gates[m];
            F4 gf = gates[HD1 + m];
            F4 gg = gates[2 * HD1 + m];
            F4 go = gates[3 * HD1 + m];
            F4 hnew;
#pragma unroll
            for (int b = 0; b < NB; b++) {
                float cn = fmaf(gf.v[b], c[b], gi.v[b] * gg.v[b]);
                c[b] = cn;
                float s2 = 1.f / (1.f + __expf(-2.f * cn)); // tanh(cn)
                float th = 2.f * s2 - 1.f;
                float h  = go.v[b] * th;
                hnew.v[b] = h;
                h1relu[((size_t)t * BATCH + b0 + b) * HD1 + m] =
                    __float2bfloat16(fmaxf(h, 0.f));
            }
            hT[m] = hnew;
        }
        __syncthreads();
    }
}

// ---------------------------------------------------------------------------
// Phase 2: LSTM layer 2 (input 80, hidden 100). One block per 4 batches.
// 512 threads: threads 0..399 own gate-rows (W_ih2 row + W_hh2 row in regs).
// Writes relu(h2) at t=511 (fp32) to workspace region 2.
// ---------------------------------------------------------------------------
__global__ __launch_bounds__(512, 2)
void lstm2_kernel(const __hip_bfloat16* __restrict__ h1relu,
                  const float* __restrict__ W_ih2,
                  const float* __restrict__ W_hh2,
                  const float* __restrict__ b_ih2,
                  const float* __restrict__ b_hh2,
                  float* __restrict__ h2last)
{
    const int j  = threadIdx.x;
    const int b0 = blockIdx.x * NB;
    const bool rowActive = (j < 4 * HD2);
    const int q = j / HD2;
    const int m = j % HD2;

    float wih[HD1];
    float whh[HD2];
    float bias = 0.f;
    if (rowActive) {
#pragma unroll
        for (int k = 0; k < HD1; k++) wih[k] = W_ih2[j * HD1 + k];
#pragma unroll
        for (int k = 0; k < HD2; k++) whh[k] = W_hh2[j * HD2 + k];
        bias = b_ih2[j] + b_hh2[j];
    }

    __shared__ F4 h1T[HD1];
    __shared__ F4 h2T[HD2];
    __shared__ F4 gates[4 * HD2];

    if (j < HD2) { h2T[j].v[0] = 0.f; h2T[j].v[1] = 0.f; h2T[j].v[2] = 0.f; h2T[j].v[3] = 0.f; }
    float c[NB] = {0.f, 0.f, 0.f, 0.f};
    __syncthreads();

    for (int t = 0; t < T_STEPS; t++) {
        // stage relu(h1)[t] for our 4 batches into LDS (transposed)
        if (j < NB * HD1) {
            int b = j / HD1, k = j % HD1;
            float v = __bfloat162float(h1relu[((size_t)t * BATCH + b0 + b) * HD1 + k]);
            h1T[k].v[b] = v;
        }
        __syncthreads();

        if (rowActive) {
            float acc[NB];
#pragma unroll
            for (int b = 0; b < NB; b++) acc[b] = bias;
#pragma unroll
            for (int k = 0; k < HD1; k++) {
                F4 hk = h1T[k];
                acc[0] = fmaf(wih[k], hk.v[0], acc[0]);
                acc[1] = fmaf(wih[k], hk.v[1], acc[1]);
                acc[2] = fmaf(wih[k], hk.v[2], acc[2]);
                acc[3] = fmaf(wih[k], hk.v[3], acc[3]);
            }
#pragma unroll
            for (int k = 0; k < HD2; k++) {
                F4 hk = h2T[k];
                acc[0] = fmaf(whh[k], hk.v[0], acc[0]);
                acc[1] = fmaf(whh[k], hk.v[1], acc[1]);
                acc[2] = fmaf(whh[k], hk.v[2], acc[2]);
                acc[3] = fmaf(whh[k], hk.v[3], acc[3]);
            }
            F4 gv;
#pragma unroll
            for (int b = 0; b < NB; b++) {
                float z  = acc[b];
                float zz = (q == 2) ? 2.f * z : z;
                float s  = 1.f / (1.f + __expf(-zz));
                gv.v[b]  = (q == 2) ? (2.f * s - 1.f) : s;
            }
            gates[j] = gv;
        }
        __syncthreads();

        if (j < HD2) {
            F4 gi = gates[m];
            F4 gf = gates[HD2 + m];
            F4 gg = gates[2 * HD2 + m];
            F4 go = gates[3 * HD2 + m];
            F4 hnew;
#pragma unroll
            for (int b = 0; b < NB; b++) {
                float cn = fmaf(gf.v[b], c[b], gi.v[b] * gg.v[b]);
                c[b] = cn;
                float s2 = 1.f / (1.f + __expf(-2.f * cn));
                float th = 2.f * s2 - 1.f;
                float h  = go.v[b] * th;
                hnew.v[b] = h;
                if (t == T_STEPS - 1)
                    h2last[(size_t)(b0 + b) * HD2 + m] = fmaxf(h, 0.f);
            }
            h2T[m] = hnew;
        }
        __syncthreads();
    }
}

// ---------------------------------------------------------------------------
// Head: out[b] = W_l2 @ relu(W_l1 @ h2last[b] + b_l1) + b_l2
// ---------------------------------------------------------------------------
__global__ __launch_bounds__(64)
void head_kernel(const float* __restrict__ h2last,
                 const float* __restrict__ W_l1,
                 const float* __restrict__ b_l1,
                 const float* __restrict__ W_l2,
                 const float* __restrict__ b_l2,
                 float* __restrict__ out)
{
    int b = blockIdx.x * 64 + threadIdx.x;
    if (b >= BATCH) return;
    const float* h = h2last + (size_t)b * HD2;
    float o = b_l2[0];
#pragma unroll
    for (int u = 0; u < 10; u++) {
        float s = b_l1[u];
#pragma unroll
        for (int k = 0; k < HD2; k++) s = fmaf(W_l1[u * HD2 + k], h[k], s);
        o = fmaf(W_l2[u], fmaxf(s, 0.f), o);
    }
    out[b] = o;
}

extern "C" void kernel_launch(void* const* d_in, const int* in_sizes, int n_in,
                              void* d_out, int out_size, void* d_ws, size_t ws_size,
                              hipStream_t stream)
{
    const float* x     = (const float*)d_in[0];
    const float* W_ih1 = (const float*)d_in[1];
    const float* W_hh1 = (const float*)d_in[2];
    const float* b_ih1 = (const float*)d_in[3];
    const float* b_hh1 = (const float*)d_in[4];
    const float* W_ih2 = (const float*)d_in[5];
    const float* W_hh2 = (const float*)d_in[6];
    const float* b_ih2 = (const float*)d_in[7];
    const float* b_hh2 = (const float*)d_in[8];
    const float* W_l1  = (const float*)d_in[9];
    const float* b_l1  = (const float*)d_in[10];
    const float* W_l2  = (const float*)d_in[11];
    const float* b_l2  = (const float*)d_in[12];
    float* out = (float*)d_out;

    // workspace: [0, 84MB) relu(h1) bf16 [t][b][k]; then h2last fp32 [b][k]
    __hip_bfloat16* h1relu = (__hip_bfloat16*)d_ws;
    size_t off = (size_t)T_STEPS * BATCH * HD1 * sizeof(__hip_bfloat16);
    float* h2last = (float*)((char*)d_ws + off);

    hipLaunchKernelGGL(lstm1_kernel, dim3(BATCH / NB), dim3(4 * HD1), 0, stream,
                       x, W_ih1, W_hh1, b_ih1, b_hh1, h1relu);
    hipLaunchKernelGGL(lstm2_kernel, dim3(BATCH / NB), dim3(512), 0, stream,
                       h1relu, W_ih2, W_hh2, b_ih2, b_hh2, h2last);
    hipLaunchKernelGGL(head_kernel, dim3(BATCH / 64), dim3(64), 0, stream,
                       h2last, W_l1, b_l1, W_l2, b_l2, out);
}

// Round 2
// 1790.453 us; speedup vs baseline: 1.7709x; 1.7709x over previous
//
#include <hip/hip_runtime.h>
#include <hip/hip_bf16.h>

#define T_STEPS 512
#define BATCH   1024
#define HD1     80
#define HD2     100
#define NB      2       // batches per block

typedef _Float16 half2_t __attribute__((ext_vector_type(2)));

union HU { unsigned int u; half2_t h; };
static __device__ __forceinline__ half2_t bch(unsigned int u) { HU x; x.u = u; return x.h; }
static __device__ __forceinline__ unsigned int bcu(half2_t h) { HU x; x.h = h; return x.u; }

static __device__ __forceinline__ float dot2(half2_t a, half2_t b, float c) {
    return __builtin_amdgcn_fdot2(a, b, c, false);
}

// ---------------------------------------------------------------------------
// Phase 1: LSTM layer 1 (input dim 1, hidden 80). 512 blocks x 320 threads,
// 2 batches/block. Thread j owns gate-row j; W_hh1 row packed f16 in 40 VGPRs.
// h state packed f16 pairs in LDS. Writes relu(h1) f16 to ws, layout [t][b][k].
// ---------------------------------------------------------------------------
__global__ __launch_bounds__(4 * HD1, 4)
void lstm1_kernel(const float* __restrict__ x,
                  const float* __restrict__ W_ih1,
                  const float* __restrict__ W_hh1,
                  const float* __restrict__ b_ih1,
                  const float* __restrict__ b_hh1,
                  _Float16* __restrict__ h1relu)
{
    const int j  = threadIdx.x;        // gate row 0..319
    const int b0 = blockIdx.x * NB;    // batch base
    const int q  = j / HD1;            // 0=i 1=f 2=g(tanh) 3=o
    const int m  = j % HD1;

    half2_t w[HD1 / 2];
#pragma unroll
    for (int k2 = 0; k2 < HD1 / 2; k2++) {
        half2_t p;
        p.x = (_Float16)W_hh1[j * HD1 + 2 * k2];
        p.y = (_Float16)W_hh1[j * HD1 + 2 * k2 + 1];
        w[k2] = p;
    }
    const float wih  = W_ih1[j];
    const float bias = b_ih1[j] + b_hh1[j];

    __shared__ uint2  hp[HD1 / 2];     // packed h pairs, [k2].{x=b0,y=b1}
    __shared__ float2 gates[4 * HD1];  // post-activation gates, per 2 batches
    __shared__ float  xs[NB][T_STEPS]; // input staged once

    if (j < HD1 / 2) hp[j] = make_uint2(0u, 0u);
    for (int idx = j; idx < NB * T_STEPS; idx += 4 * HD1) {
        int b = idx >> 9, t = idx & (T_STEPS - 1);
        xs[b][t] = x[(size_t)(b0 + b) * T_STEPS + t];
    }
    float c0 = 0.f, c1 = 0.f;
    __syncthreads();

    for (int t = 0; t < T_STEPS; t++) {
        float acc0 = fmaf(wih, xs[0][t], bias);
        float acc1 = fmaf(wih, xs[1][t], bias);
#pragma unroll
        for (int k2 = 0; k2 < HD1 / 2; k2++) {
            uint2 u = hp[k2];
            acc0 = dot2(w[k2], bch(u.x), acc0);
            acc1 = dot2(w[k2], bch(u.y), acc1);
        }
        // uniform activation: tanh(z) = 2*sigmoid(2z)-1
        float z0 = (q == 2) ? 2.f * acc0 : acc0;
        float z1 = (q == 2) ? 2.f * acc1 : acc1;
        float s0 = 1.f / (1.f + __expf(-z0));
        float s1 = 1.f / (1.f + __expf(-z1));
        float g0 = (q == 2) ? (2.f * s0 - 1.f) : s0;
        float g1 = (q == 2) ? (2.f * s1 - 1.f) : s1;
        gates[j] = make_float2(g0, g1);
        __syncthreads();

        if (j < HD1) {
            float2 gi = gates[m];
            float2 gf = gates[HD1 + m];
            float2 gg = gates[2 * HD1 + m];
            float2 go = gates[3 * HD1 + m];
            c0 = fmaf(gf.x, c0, gi.x * gg.x);
            c1 = fmaf(gf.y, c1, gi.y * gg.y);
            float t0 = 2.f / (1.f + __expf(-2.f * c0)) - 1.f;
            float t1 = 2.f / (1.f + __expf(-2.f * c1)) - 1.f;
            float h0 = go.x * t0;
            float h1 = go.y * t1;
            // pack pairs (m even gets m+1's values via shuffle)
            float h0n = __shfl_down(h0, 1, 64);
            float h1n = __shfl_down(h1, 1, 64);
            if ((m & 1) == 0) {
                half2_t p0; p0.x = (_Float16)h0; p0.y = (_Float16)h0n;
                half2_t p1; p1.x = (_Float16)h1; p1.y = (_Float16)h1n;
                hp[m >> 1] = make_uint2(bcu(p0), bcu(p1));
                // relu'd copies to global, packed 4B stores
                half2_t r0; r0.x = (_Float16)fmaxf(h0, 0.f); r0.y = (_Float16)fmaxf(h0n, 0.f);
                half2_t r1; r1.x = (_Float16)fmaxf(h1, 0.f); r1.y = (_Float16)fmaxf(h1n, 0.f);
                unsigned int* g0p = (unsigned int*)(h1relu + ((size_t)t * BATCH + b0) * HD1);
                unsigned int* g1p = (unsigned int*)(h1relu + ((size_t)t * BATCH + b0 + 1) * HD1);
                g0p[m >> 1] = bcu(r0);
                g1p[m >> 1] = bcu(r1);
            }
        }
        __syncthreads();
    }
}

// ---------------------------------------------------------------------------
// Phase 2: LSTM layer 2 (input 80, hidden 100). 512 blocks x 448 threads,
// 2 batches/block. Thread j<400 owns gate-row j; W_ih2+W_hh2 rows packed f16
// in 90 VGPRs. h1 prefetched one step ahead into registers.
// ---------------------------------------------------------------------------
__global__ __launch_bounds__(448, 4)
void lstm2_kernel(const _Float16* __restrict__ h1relu,
                  const float* __restrict__ W_ih2,
                  const float* __restrict__ W_hh2,
                  const float* __restrict__ b_ih2,
                  const float* __restrict__ b_hh2,
                  float* __restrict__ h2last)
{
    const int j  = threadIdx.x;
    const int b0 = blockIdx.x * NB;
    const bool rowActive = (j < 4 * HD2);
    const int q = j / HD2;
    const int m = j % HD2;

    half2_t wih[HD1 / 2];
    half2_t whh[HD2 / 2];
    float bias = 0.f;
    if (rowActive) {
#pragma unroll
        for (int k2 = 0; k2 < HD1 / 2; k2++) {
            half2_t p;
            p.x = (_Float16)W_ih2[j * HD1 + 2 * k2];
            p.y = (_Float16)W_ih2[j * HD1 + 2 * k2 + 1];
            wih[k2] = p;
        }
#pragma unroll
        for (int k2 = 0; k2 < HD2 / 2; k2++) {
            half2_t p;
            p.x = (_Float16)W_hh2[j * HD2 + 2 * k2];
            p.y = (_Float16)W_hh2[j * HD2 + 2 * k2 + 1];
            whh[k2] = p;
        }
        bias = b_ih2[j] + b_hh2[j];
    }

    __shared__ uint2  h1p[HD1 / 2];    // packed relu(h1) pairs [k2].{b0,b1}
    __shared__ uint2  h2p[HD2 / 2];    // packed h2 pairs
    __shared__ float2 gates[4 * HD2];

    if (j < HD2 / 2) h2p[j] = make_uint2(0u, 0u);
    float c0 = 0.f, c1 = 0.f;

    // prefetch h1[t=0] pairs: threads 0..79, b=j/40, k2=j%40
    unsigned int pf = 0;
    const int pb = j / (HD1 / 2), pk2 = j % (HD1 / 2);
    if (j < NB * (HD1 / 2))
        pf = *(const unsigned int*)(h1relu + ((size_t)0 * BATCH + b0 + pb) * HD1 + 2 * pk2);

    for (int t = 0; t < T_STEPS; t++) {
        if (j < NB * (HD1 / 2)) {
            ((unsigned int*)h1p)[2 * pk2 + pb] = pf;   // uint2 = {b0,b1}
        }
        __syncthreads();   // h1p + h2p ready
        if (j < NB * (HD1 / 2) && t + 1 < T_STEPS)
            pf = *(const unsigned int*)(h1relu + ((size_t)(t + 1) * BATCH + b0 + pb) * HD1 + 2 * pk2);

        if (rowActive) {
            float acc0 = bias, acc1 = bias;
#pragma unroll
            for (int k2 = 0; k2 < HD1 / 2; k2++) {
                uint2 u = h1p[k2];
                acc0 = dot2(wih[k2], bch(u.x), acc0);
                acc1 = dot2(wih[k2], bch(u.y), acc1);
            }
#pragma unroll
            for (int k2 = 0; k2 < HD2 / 2; k2++) {
                uint2 u = h2p[k2];
                acc0 = dot2(whh[k2], bch(u.x), acc0);
                acc1 = dot2(whh[k2], bch(u.y), acc1);
            }
            float z0 = (q == 2) ? 2.f * acc0 : acc0;
            float z1 = (q == 2) ? 2.f * acc1 : acc1;
            float s0 = 1.f / (1.f + __expf(-z0));
            float s1 = 1.f / (1.f + __expf(-z1));
            gates[j] = make_float2((q == 2) ? (2.f * s0 - 1.f) : s0,
                                   (q == 2) ? (2.f * s1 - 1.f) : s1);
        }
        __syncthreads();   // gates ready

        if (j < HD2) {
            float2 gi = gates[m];
            float2 gf = gates[HD2 + m];
            float2 gg = gates[2 * HD2 + m];
            float2 go = gates[3 * HD2 + m];
            c0 = fmaf(gf.x, c0, gi.x * gg.x);
            c1 = fmaf(gf.y, c1, gi.y * gg.y);
            float t0 = 2.f / (1.f + __expf(-2.f * c0)) - 1.f;
            float t1 = 2.f / (1.f + __expf(-2.f * c1)) - 1.f;
            float h0 = go.x * t0;
            float h1 = go.y * t1;
            float h0n = __shfl_down(h0, 1, 64);
            float h1n = __shfl_down(h1, 1, 64);
            if ((m & 1) == 0) {
                half2_t p0; p0.x = (_Float16)h0; p0.y = (_Float16)h0n;
                half2_t p1; p1.x = (_Float16)h1; p1.y = (_Float16)h1n;
                h2p[m >> 1] = make_uint2(bcu(p0), bcu(p1));
            }
            if (t == T_STEPS - 1) {
                h2last[(size_t)(b0 + 0) * HD2 + m] = fmaxf(h0, 0.f);
                h2last[(size_t)(b0 + 1) * HD2 + m] = fmaxf(h1, 0.f);
            }
        }
        __syncthreads();   // h2p stable before next staging
    }
}

// ---------------------------------------------------------------------------
// Head: out[b] = W_l2 @ relu(W_l1 @ h2last[b] + b_l1) + b_l2
// ---------------------------------------------------------------------------
__global__ __launch_bounds__(64)
void head_kernel(const float* __restrict__ h2last,
                 const float* __restrict__ W_l1,
                 const float* __restrict__ b_l1,
                 const float* __restrict__ W_l2,
                 const float* __restrict__ b_l2,
                 float* __restrict__ out)
{
    int b = blockIdx.x * 64 + threadIdx.x;
    if (b >= BATCH) return;
    const float* h = h2last + (size_t)b * HD2;
    float o = b_l2[0];
#pragma unroll
    for (int u = 0; u < 10; u++) {
        float s = b_l1[u];
#pragma unroll
        for (int k = 0; k < HD2; k++) s = fmaf(W_l1[u * HD2 + k], h[k], s);
        o = fmaf(W_l2[u], fmaxf(s, 0.f), o);
    }
    out[b] = o;
}

extern "C" void kernel_launch(void* const* d_in, const int* in_sizes, int n_in,
                              void* d_out, int out_size, void* d_ws, size_t ws_size,
                              hipStream_t stream)
{
    const float* x     = (const float*)d_in[0];
    const float* W_ih1 = (const float*)d_in[1];
    const float* W_hh1 = (const float*)d_in[2];
    const float* b_ih1 = (const float*)d_in[3];
    const float* b_hh1 = (const float*)d_in[4];
    const float* W_ih2 = (const float*)d_in[5];
    const float* W_hh2 = (const float*)d_in[6];
    const float* b_ih2 = (const float*)d_in[7];
    const float* b_hh2 = (const float*)d_in[8];
    const float* W_l1  = (const float*)d_in[9];
    const float* b_l1  = (const float*)d_in[10];
    const float* W_l2  = (const float*)d_in[11];
    const float* b_l2  = (const float*)d_in[12];
    float* out = (float*)d_out;

    // workspace: [0, 84MB) relu(h1) f16 [t][b][k]; then h2last fp32 [b][k]
    _Float16* h1relu = (_Float16*)d_ws;
    size_t off = (size_t)T_STEPS * BATCH * HD1 * sizeof(_Float16);
    float* h2last = (float*)((char*)d_ws + off);

    hipLaunchKernelGGL(lstm1_kernel, dim3(BATCH / NB), dim3(4 * HD1), 0, stream,
                       x, W_ih1, W_hh1, b_ih1, b_hh1, h1relu);
    hipLaunchKernelGGL(lstm2_kernel, dim3(BATCH / NB), dim3(448), 0, stream,
                       h1relu, W_ih2, W_hh2, b_ih2, b_hh2, h2last);
    hipLaunchKernelGGL(head_kernel, dim3(BATCH / 64), dim3(64), 0, stream,
                       h2last, W_l1, b_l1, W_l2, b_l2, out);
}